// Round 1
// baseline (86.125 us; speedup 1.0000x reference)
//
#include <hip/hip_runtime.h>

#define BS 64
#define NQ 300
#define NC 2
#define TT 16
#define NTGT (BS*TT)      // 1024
#define MCOL 300          // hungarian cols (queries)
#define NROW 16           // hungarian rows (targets)
#define STR 304           // LDS row stride for ca (17 rows used)
#define BIGF 1000000000.0f

// ---------------- Kernel 1: cost matrix ----------------
// C[q, t] = L1(pred_box[q], tgt_box[t]) - GIoU(q,t) - softmax(logits[q])[0]
__global__ __launch_bounds__(256) void cost_kernel(
    const float* __restrict__ logits,
    const float* __restrict__ boxes,
    const float* __restrict__ tgt,
    float* __restrict__ C)
{
    int q = blockIdx.x >> 2;                          // 0..19199 (uniform per block)
    int t = ((blockIdx.x & 3) << 8) | threadIdx.x;    // 0..1023

    float l0 = logits[2*q+0], l1 = logits[2*q+1];
    float mx = fmaxf(l0, l1);
    float e0 = expf(l0 - mx), e1 = expf(l1 - mx);
    float p0 = e0 / (e0 + e1);

    float4 pb = *(const float4*)(boxes + 4*(size_t)q);
    float4 tb = *(const float4*)(tgt + 4*(size_t)t);

    float cbbox = fabsf(pb.x-tb.x) + fabsf(pb.y-tb.y) + fabsf(pb.z-tb.z) + fabsf(pb.w-tb.w);

    // cxcywh -> xyxy
    float px1 = pb.x - 0.5f*pb.z, py1 = pb.y - 0.5f*pb.w;
    float px2 = pb.x + 0.5f*pb.z, py2 = pb.y + 0.5f*pb.w;
    float tx1 = tb.x - 0.5f*tb.z, ty1 = tb.y - 0.5f*tb.w;
    float tx2 = tb.x + 0.5f*tb.z, ty2 = tb.y + 0.5f*tb.w;

    float area1 = (px2-px1)*(py2-py1);
    float area2 = (tx2-tx1)*(ty2-ty1);
    float ltx = fmaxf(px1,tx1), lty = fmaxf(py1,ty1);
    float rbx = fminf(px2,tx2), rby = fminf(py2,ty2);
    float iw = fmaxf(rbx-ltx, 0.f), ih = fmaxf(rby-lty, 0.f);
    float inter = iw*ih;
    float uni = area1 + area2 - inter;
    float iou = inter/uni;
    float ex1 = fminf(px1,tx1), ey1 = fminf(py1,ty1);
    float ex2 = fmaxf(px2,tx2), ey2 = fmaxf(py2,ty2);
    float ew = fmaxf(ex2-ex1, 0.f), eh = fmaxf(ey2-ey1, 0.f);
    float areae = ew*eh;
    float giou = iou - (areae - uni)/areae;

    C[(size_t)q*NTGT + t] = cbbox - giou - p0;
}

// ---------------- Kernel 2: Hungarian (JV) per batch ----------------
// One wave (64 lanes) per batch. Each lane owns columns j = lane + 64k, k=0..4
// (j in 0..300). minv/used/v in registers; ca/p/way/u in LDS.
__global__ __launch_bounds__(64) void hungarian_kernel(
    const float* __restrict__ C, float* __restrict__ out)
{
    const int b = blockIdx.x;
    const int lane = threadIdx.x;

    __shared__ float ca[17*STR];   // (n+1) x (m+1) padded
    __shared__ float u[32];        // dual for rows, 0..16 used
    __shared__ int   p[STR];       // col -> assigned row (0 = free)
    __shared__ int   way[STR];

    // --- stage ---
    for (int j = lane; j <= MCOL; j += 64) ca[j] = 0.f;            // row 0
    if (lane <= NROW) { ca[lane*STR] = 0.f; u[lane] = 0.f; }       // col 0, u=0
    for (int idx = lane; idx < NROW*MCOL; idx += 64) {
        int q = idx >> 4;       // 0..299
        int t = idx & 15;       // 0..15
        float c = C[((size_t)(b*NQ + q))*NTGT + (b*TT + t)];
        ca[(1+t)*STR + 1 + q] = c;
    }
    for (int j = lane; j <= MCOL; j += 64) p[j] = 0;

    float vloc[5], minv[5];
    #pragma unroll
    for (int k = 0; k < 5; ++k) vloc[k] = 0.f;
    __syncthreads();

    for (int i = 1; i <= NROW; ++i) {
        if (lane == 0) p[0] = i;
        unsigned usedm = 0;
        #pragma unroll
        for (int k = 0; k < 5; ++k) minv[k] = BIGF;
        for (int j = lane; j <= MCOL; j += 64) way[j] = 0;
        __syncthreads();

        int j0 = 0;
        for (;;) {
            int i0 = p[j0];              // uniform broadcast read
            if (i0 == 0) break;
            // mark j0 used
            #pragma unroll
            for (int k = 0; k < 5; ++k)
                if (lane + 64*k == j0) usedm |= (1u << k);
            float ui0 = u[i0];

            float bestv = BIGF; int bestj = 0x7fffffff;
            #pragma unroll
            for (int k = 0; k < 5; ++k) {
                int j = lane + 64*k;
                bool act = (j <= MCOL);
                bool us  = (usedm >> k) & 1;
                float cur = act ? (ca[i0*STR + j] - ui0 - vloc[k]) : BIGF;
                if (act && !us && cur < minv[k]) { minv[k] = cur; way[j] = j0; }
                float mk = (act && !us) ? minv[k] : BIGF;
                if (mk < bestv) { bestv = mk; bestj = j; }   // ascending j per lane
            }
            // wave argmin, tie -> smallest index (matches jnp.argmin)
            #pragma unroll
            for (int off = 32; off >= 1; off >>= 1) {
                float ov = __shfl_xor(bestv, off, 64);
                int   oj = __shfl_xor(bestj, off, 64);
                if (ov < bestv || (ov == bestv && oj < bestj)) { bestv = ov; bestj = oj; }
            }
            float delta = bestv;
            int j1 = bestj;

            #pragma unroll
            for (int k = 0; k < 5; ++k) {
                int j = lane + 64*k;
                if (j <= MCOL) {
                    if ((usedm >> k) & 1) {
                        int pj = p[j];                 // distinct rows across used cols
                        atomicAdd(&u[pj], delta);
                        vloc[k] -= delta;
                    } else {
                        minv[k] -= delta;
                    }
                }
            }
            j0 = j1;
            __syncthreads();
        }
        // augment along way[] back to the root
        while (j0 != 0) {
            int jn  = way[j0];     // uniform
            int pjn = p[jn];
            __syncthreads();
            if (lane == 0) p[j0] = pjn;
            __syncthreads();
            j0 = jn;
        }
        __syncthreads();
    }

    // --- extract row_ind / col_ind (ascending query order) ---
    const size_t ROWB = (size_t)BS*NQ*NTGT;          // 19,660,800
    const size_t COLB = ROWB + (size_t)BS*TT;
    int base = 0;
    #pragma unroll
    for (int k = 0; k < 5; ++k) {
        int q = lane + 64*k;
        int a = (q < MCOL) ? p[1+q] : 0;
        unsigned long long mb = __ballot(a > 0);
        int pos = base + __popcll(mb & ((1ull << lane) - 1ull));
        if (a > 0) {
            out[ROWB + (size_t)b*TT + pos] = (float)q;
            out[COLB + (size_t)b*TT + pos] = (float)(a - 1);
        }
        base += __popcll(mb);
    }
}

extern "C" void kernel_launch(void* const* d_in, const int* in_sizes, int n_in,
                              void* d_out, int out_size, void* d_ws, size_t ws_size,
                              hipStream_t stream) {
    const float* logits = (const float*)d_in[0];   // (64,300,2)
    const float* boxes  = (const float*)d_in[1];   // (64,300,4)
    const float* tgt    = (const float*)d_in[2];   // (1024,4)
    float* out = (float*)d_out;

    cost_kernel<<<dim3(BS*NQ*4), 256, 0, stream>>>(logits, boxes, tgt, out);
    hungarian_kernel<<<dim3(BS), 64, 0, stream>>>(out, out);
}

// Round 2
// 50.544 us; speedup vs baseline: 1.7040x; 1.7040x over previous
//
#include <hip/hip_runtime.h>

#define BS 64
#define NQ 300
#define NTGT 1024
#define TT 16
#define MCOL 300
#define NROW 16
#define STR 304
#define BIGF 1000000000.0f

// ---- shared per-cell cost (identical formula in both paths) ----
__device__ __forceinline__ float cell_cost(float p0, float pcx, float pcy, float pw, float ph,
                                           float px1, float py1, float px2, float py2, float parea,
                                           float4 tb)
{
    float cb = fabsf(pcx - tb.x) + fabsf(pcy - tb.y) + fabsf(pw - tb.z) + fabsf(ph - tb.w);
    float tx1 = tb.x - 0.5f*tb.z, ty1 = tb.y - 0.5f*tb.w;
    float tx2 = tb.x + 0.5f*tb.z, ty2 = tb.y + 0.5f*tb.w;
    float tarea = (tx2 - tx1) * (ty2 - ty1);
    float ltx = fmaxf(px1, tx1), lty = fmaxf(py1, ty1);
    float rbx = fminf(px2, tx2), rby = fminf(py2, ty2);
    float iw = fmaxf(rbx - ltx, 0.f), ih = fmaxf(rby - lty, 0.f);
    float inter = iw * ih;
    float uni = parea + tarea - inter;
    float iou = inter * __builtin_amdgcn_rcpf(uni);
    float ex1 = fminf(px1, tx1), ey1 = fminf(py1, ty1);
    float ex2 = fmaxf(px2, tx2), ey2 = fmaxf(py2, ty2);
    float areae = (ex2 - ex1) * (ey2 - ey1);
    float giou = iou - (areae - uni) * __builtin_amdgcn_rcpf(areae);
    return cb - giou - p0;
}

// static-index select chains (rule #20: no runtime-indexed register arrays)
__device__ __forceinline__ int sel5i(const int a[5], int k0) {
    int r = a[0];
    r = (k0 == 1) ? a[1] : r;
    r = (k0 == 2) ? a[2] : r;
    r = (k0 == 3) ? a[3] : r;
    r = (k0 == 4) ? a[4] : r;
    return r;
}
__device__ __forceinline__ float sel5f(const float a[5], int k0) {
    float r = a[0];
    r = (k0 == 1) ? a[1] : r;
    r = (k0 == 2) ? a[2] : r;
    r = (k0 == 3) ? a[3] : r;
    r = (k0 == 4) ? a[4] : r;
    return r;
}

__global__ __launch_bounds__(256) void fused_kernel(
    const float* __restrict__ logits,
    const float* __restrict__ boxes,
    const float* __restrict__ tgt,
    float* __restrict__ out)
{
    // LDS for the hungarian blocks' 16x300 cost tile (rows=t 0..15, col 0 = dummy)
    __shared__ float ca[16 * STR + 32];
    const int tid = threadIdx.x;

    if (blockIdx.x >= BS) {
        // ================= cost-matrix path: one q per block, 4 t per thread ==========
        int q = blockIdx.x - BS;                     // 0..19199, uniform per block
        float l0v = logits[2*q], l1v = logits[2*q + 1];
        float p0 = __builtin_amdgcn_rcpf(1.f + __expf(l1v - l0v));   // softmax[0]
        float4 pb = ((const float4*)boxes)[q];
        float px1 = pb.x - 0.5f*pb.z, py1 = pb.y - 0.5f*pb.w;
        float px2 = pb.x + 0.5f*pb.z, py2 = pb.y + 0.5f*pb.w;
        float parea = (px2 - px1) * (py2 - py1);

        int t0 = tid << 2;
        const float4* tgt4 = (const float4*)tgt;
        float4 tb0 = tgt4[t0+0], tb1 = tgt4[t0+1], tb2 = tgt4[t0+2], tb3 = tgt4[t0+3];
        float4 r;
        r.x = cell_cost(p0, pb.x, pb.y, pb.z, pb.w, px1, py1, px2, py2, parea, tb0);
        r.y = cell_cost(p0, pb.x, pb.y, pb.z, pb.w, px1, py1, px2, py2, parea, tb1);
        r.z = cell_cost(p0, pb.x, pb.y, pb.z, pb.w, px1, py1, px2, py2, parea, tb2);
        r.w = cell_cost(p0, pb.x, pb.y, pb.z, pb.w, px1, py1, px2, py2, parea, tb3);
        *(float4*)(out + (size_t)q * NTGT + t0) = r;
        return;
    }

    // ================= hungarian path: block b handles batch b =======================
    const int b = blockIdx.x;

    // ---- prologue: all 4 waves compute this batch's 16x300 tile into LDS ----
    {
        auto fill_row = [&](int q) {
            float l0v = logits[(b*NQ + q)*2 + 0], l1v = logits[(b*NQ + q)*2 + 1];
            float p0 = __builtin_amdgcn_rcpf(1.f + __expf(l1v - l0v));
            float4 pb = ((const float4*)boxes)[b*NQ + q];
            float px1 = pb.x - 0.5f*pb.z, py1 = pb.y - 0.5f*pb.w;
            float px2 = pb.x + 0.5f*pb.z, py2 = pb.y + 0.5f*pb.w;
            float parea = (px2 - px1) * (py2 - py1);
            #pragma unroll
            for (int t = 0; t < TT; ++t) {
                float4 tb = ((const float4*)tgt)[b*TT + t];
                ca[t*STR + 1 + q] =
                    cell_cost(p0, pb.x, pb.y, pb.z, pb.w, px1, py1, px2, py2, parea, tb);
            }
        };
        fill_row(tid);                      // q = 0..255
        if (tid >= 212) fill_row(tid + 44); // q = 256..299 (done by wave 3, not wave 0)
        if (tid < 16) ca[tid*STR] = 0.f;    // dummy col 0
    }
    __syncthreads();
    if (tid >= 64) return;                  // waves 1..3 done; wave 0 runs JV, barrier-free

    // ---- register-only JV shortest-augmenting-path ----
    // lane owns cols j = lane + 64k, k=0..4 (j <= 300). u[row] lives in lane 'row'.
    const int lane = tid;
    int   p_reg[5]   = {0,0,0,0,0};
    int   way_reg[5] = {0,0,0,0,0};
    float vloc[5]    = {0.f,0.f,0.f,0.f,0.f};
    float minv[5], ur_reg[5];
    float u_lane = 0.f;

    for (int i = 1; i <= NROW; ++i) {
        if (lane == 0) p_reg[0] = i;        // virtual col 0 <- current row
        unsigned usedm = 0, treemask = 0;
        #pragma unroll
        for (int k = 0; k < 5; ++k) { minv[k] = BIGF; way_reg[k] = 0; }
        #pragma unroll
        for (int k = 0; k < 5; ++k) ur_reg[k] = __shfl(u_lane, p_reg[k], 64); // u[p[j]]

        int j0 = 0;
        for (;;) {
            int l0 = j0 & 63, k0 = j0 >> 6;                 // uniform
            int i0 = __shfl(sel5i(p_reg, k0), l0, 64);
            if (i0 == 0) break;
            float ui0 = __shfl(sel5f(ur_reg, k0), l0, 64);
            #pragma unroll
            for (int k = 0; k < 5; ++k)
                if (k == k0 && lane == l0) usedm |= (1u << k);
            treemask |= (1u << i0);

            int rowbase = (i0 - 1) * STR;
            float cur[5];
            #pragma unroll
            for (int k = 0; k < 5; ++k) cur[k] = ca[rowbase + lane + (k << 6)];

            float bestv = BIGF; int bestj = 0x7FFFFFFF;
            #pragma unroll
            for (int k = 0; k < 5; ++k) {
                int j = lane + (k << 6);
                bool act = (j <= MCOL);
                bool us  = ((usedm >> k) & 1u) != 0u;
                float cu = cur[k] - ui0 - vloc[k];
                if (act && !us && cu < minv[k]) { minv[k] = cu; way_reg[k] = j0; }
                float mk = (act && !us) ? minv[k] : BIGF;
                if (mk < bestv) { bestv = mk; bestj = j; }  // ascending j per lane
            }
            // wave argmin, tie -> smallest j (matches jnp.argmin)
            #pragma unroll
            for (int off = 32; off >= 1; off >>= 1) {
                float ov = __shfl_xor(bestv, off, 64);
                int   oj = __shfl_xor(bestj, off, 64);
                if (ov < bestv || (ov == bestv && oj < bestj)) { bestv = ov; bestj = oj; }
            }
            float delta = bestv;
            #pragma unroll
            for (int k = 0; k < 5; ++k) {
                bool us = ((usedm >> k) & 1u) != 0u;
                if (us) { vloc[k] -= delta; ur_reg[k] += delta; }
                else if (lane + (k << 6) <= MCOL) minv[k] -= delta;
            }
            if (lane <= NROW && ((treemask >> lane) & 1u)) u_lane += delta; // u[tree rows]+=d
            j0 = bestj;
        }
        // augment: p[j0] = p[way[j0]] walking back to col 0 (all via shuffles)
        while (j0 != 0) {
            int l0 = j0 & 63, k0 = j0 >> 6;
            int jn = __shfl(sel5i(way_reg, k0), l0, 64);
            int pn = __shfl(sel5i(p_reg, jn >> 6), jn & 63, 64);
            #pragma unroll
            for (int k = 0; k < 5; ++k)
                if (k == k0 && lane == l0) p_reg[k] = pn;
            j0 = jn;
        }
    }

    // ---- extraction: row_ind/col_ind in ascending query order ----
    const size_t ROWB = (size_t)BS * NQ * NTGT;
    const size_t COLB = ROWB + (size_t)BS * TT;
    int base = 0;
    #pragma unroll
    for (int k = 0; k < 5; ++k) {
        int pk1 = (k < 4) ? __shfl(p_reg[k + 1], 0, 64) : 0;   // p[64(k+1)]
        int psh = __shfl(p_reg[k], (lane + 1) & 63, 64);       // p[64k + lane+1] (lane<63)
        int q = (k << 6) | lane;
        int a = (lane == 63) ? pk1 : psh;                      // = p[q+1]
        if (q >= MCOL) a = 0;
        unsigned long long mb = __ballot(a > 0);
        int pos = base + __popcll(mb & ((1ull << lane) - 1ull));
        if (a > 0) {
            out[ROWB + (size_t)b * TT + pos] = (float)q;
            out[COLB + (size_t)b * TT + pos] = (float)(a - 1);
        }
        base += __popcll(mb);
    }
}

extern "C" void kernel_launch(void* const* d_in, const int* in_sizes, int n_in,
                              void* d_out, int out_size, void* d_ws, size_t ws_size,
                              hipStream_t stream) {
    const float* logits = (const float*)d_in[0];   // (64,300,2)
    const float* boxes  = (const float*)d_in[1];   // (64,300,4)
    const float* tgt    = (const float*)d_in[2];   // (1024,4)
    float* out = (float*)d_out;

    // blocks 0..63: hungarian (self-contained); blocks 64..19263: cost matrix (1 q each)
    fused_kernel<<<dim3(BS + BS*NQ), 256, 0, stream>>>(logits, boxes, tgt, out);
}

// Round 3
// 31.312 us; speedup vs baseline: 2.7505x; 1.6142x over previous
//
#include <hip/hip_runtime.h>

#define BS 64
#define NQ 300
#define NTGT 1024
#define TT 16
#define MCOL 300
#define NROW 16
#define STR 304
#define BIGF 1000000000.0f

// ---- shared per-cell cost (identical formula in both paths) ----
__device__ __forceinline__ float cell_cost(float p0, float pcx, float pcy, float pw, float ph,
                                           float px1, float py1, float px2, float py2, float parea,
                                           float4 tb)
{
    float cb = fabsf(pcx - tb.x) + fabsf(pcy - tb.y) + fabsf(pw - tb.z) + fabsf(ph - tb.w);
    float tx1 = tb.x - 0.5f*tb.z, ty1 = tb.y - 0.5f*tb.w;
    float tx2 = tb.x + 0.5f*tb.z, ty2 = tb.y + 0.5f*tb.w;
    float tarea = (tx2 - tx1) * (ty2 - ty1);
    float ltx = fmaxf(px1, tx1), lty = fmaxf(py1, ty1);
    float rbx = fminf(px2, tx2), rby = fminf(py2, ty2);
    float iw = fmaxf(rbx - ltx, 0.f), ih = fmaxf(rby - lty, 0.f);
    float inter = iw * ih;
    float uni = parea + tarea - inter;
    float iou = inter * __builtin_amdgcn_rcpf(uni);
    float ex1 = fminf(px1, tx1), ey1 = fminf(py1, ty1);
    float ex2 = fmaxf(px2, tx2), ey2 = fmaxf(py2, ty2);
    float areae = (ex2 - ex1) * (ey2 - ey1);
    float giou = iou - (areae - uni) * __builtin_amdgcn_rcpf(areae);
    return cb - giou - p0;
}

// ---- DPP wave-64 min reductions (result valid in lane 63) ----
template<int CTRL>
__device__ __forceinline__ float dppmin_f(float x) {
    int t = __builtin_amdgcn_update_dpp(__float_as_int(BIGF), __float_as_int(x),
                                        CTRL, 0xF, 0xF, false);
    return fminf(x, __int_as_float(t));
}
template<int CTRL>
__device__ __forceinline__ int dppmin_i(int x) {
    int t = __builtin_amdgcn_update_dpp(0x7FFFFFFF, x, CTRL, 0xF, 0xF, false);
    return (t < x) ? t : x;
}
__device__ __forceinline__ float wave_min_f(float x) {
    x = dppmin_f<0x111>(x);  // row_shr:1
    x = dppmin_f<0x112>(x);  // row_shr:2
    x = dppmin_f<0x114>(x);  // row_shr:4
    x = dppmin_f<0x118>(x);  // row_shr:8
    x = dppmin_f<0x142>(x);  // row_bcast:15
    x = dppmin_f<0x143>(x);  // row_bcast:31
    return x;
}
__device__ __forceinline__ int wave_min_i(int x) {
    x = dppmin_i<0x111>(x);
    x = dppmin_i<0x112>(x);
    x = dppmin_i<0x114>(x);
    x = dppmin_i<0x118>(x);
    x = dppmin_i<0x142>(x);
    x = dppmin_i<0x143>(x);
    return x;
}

// ---- uniform-index gather from a 5-reg distributed array via v_readlane ----
// k0, l0 are wave-uniform. Returns a uniform value = a[k0] of lane l0.
__device__ __forceinline__ int rl5(const int a[5], int k0, int l0) {
    int r0 = __builtin_amdgcn_readlane(a[0], l0);
    int r1 = __builtin_amdgcn_readlane(a[1], l0);
    int r2 = __builtin_amdgcn_readlane(a[2], l0);
    int r3 = __builtin_amdgcn_readlane(a[3], l0);
    int r4 = __builtin_amdgcn_readlane(a[4], l0);
    int r = r0;
    r = (k0 == 1) ? r1 : r;
    r = (k0 == 2) ? r2 : r;
    r = (k0 == 3) ? r3 : r;
    r = (k0 == 4) ? r4 : r;
    return r;
}
__device__ __forceinline__ float rl5f(const float a[5], int k0, int l0) {
    int ai[5] = { __float_as_int(a[0]), __float_as_int(a[1]), __float_as_int(a[2]),
                  __float_as_int(a[3]), __float_as_int(a[4]) };
    return __int_as_float(rl5(ai, k0, l0));
}

__global__ __launch_bounds__(256) void fused_kernel(
    const float* __restrict__ logits,
    const float* __restrict__ boxes,
    const float* __restrict__ tgt,
    float* __restrict__ out)
{
    __shared__ float ca[16 * STR + 32];
    const int tid = threadIdx.x;

    if (blockIdx.x >= BS) {
        // ================= cost-matrix path: one q per block, 4 t per thread ==========
        int q = blockIdx.x - BS;                     // 0..19199, uniform per block
        float l0v = logits[2*q], l1v = logits[2*q + 1];
        float p0 = __builtin_amdgcn_rcpf(1.f + __expf(l1v - l0v));   // softmax[0]
        float4 pb = ((const float4*)boxes)[q];
        float px1 = pb.x - 0.5f*pb.z, py1 = pb.y - 0.5f*pb.w;
        float px2 = pb.x + 0.5f*pb.z, py2 = pb.y + 0.5f*pb.w;
        float parea = (px2 - px1) * (py2 - py1);

        int t0 = tid << 2;
        const float4* tgt4 = (const float4*)tgt;
        float4 tb0 = tgt4[t0+0], tb1 = tgt4[t0+1], tb2 = tgt4[t0+2], tb3 = tgt4[t0+3];
        float4 r;
        r.x = cell_cost(p0, pb.x, pb.y, pb.z, pb.w, px1, py1, px2, py2, parea, tb0);
        r.y = cell_cost(p0, pb.x, pb.y, pb.z, pb.w, px1, py1, px2, py2, parea, tb1);
        r.z = cell_cost(p0, pb.x, pb.y, pb.z, pb.w, px1, py1, px2, py2, parea, tb2);
        r.w = cell_cost(p0, pb.x, pb.y, pb.z, pb.w, px1, py1, px2, py2, parea, tb3);
        *(float4*)(out + (size_t)q * NTGT + t0) = r;
        return;
    }

    // ================= hungarian path: block b handles batch b =======================
    const int b = blockIdx.x;

    {
        auto fill_row = [&](int q) {
            float l0v = logits[(b*NQ + q)*2 + 0], l1v = logits[(b*NQ + q)*2 + 1];
            float p0 = __builtin_amdgcn_rcpf(1.f + __expf(l1v - l0v));
            float4 pb = ((const float4*)boxes)[b*NQ + q];
            float px1 = pb.x - 0.5f*pb.z, py1 = pb.y - 0.5f*pb.w;
            float px2 = pb.x + 0.5f*pb.z, py2 = pb.y + 0.5f*pb.w;
            float parea = (px2 - px1) * (py2 - py1);
            #pragma unroll
            for (int t = 0; t < TT; ++t) {
                float4 tb = ((const float4*)tgt)[b*TT + t];
                ca[t*STR + 1 + q] =
                    cell_cost(p0, pb.x, pb.y, pb.z, pb.w, px1, py1, px2, py2, parea, tb);
            }
        };
        fill_row(tid);                      // q = 0..255
        if (tid >= 212) fill_row(tid + 44); // q = 256..299
        if (tid < 16) ca[tid*STR] = 0.f;    // dummy col 0
    }
    __syncthreads();
    if (tid >= 64) return;                  // wave 0 runs JV, barrier-free

    __builtin_amdgcn_s_setprio(1);

    // ---- register-only JV shortest-augmenting-path ----
    const int lane = tid;
    int   p_reg[5]   = {0,0,0,0,0};
    int   way_reg[5] = {0,0,0,0,0};
    float vloc[5]    = {0.f,0.f,0.f,0.f,0.f};
    float minv[5], ur_reg[5];
    float u_lane = 0.f;

    for (int i = 1; i <= NROW; ++i) {
        if (lane == 0) p_reg[0] = i;
        unsigned usedm = 0, treemask = 0;
        #pragma unroll
        for (int k = 0; k < 5; ++k) { minv[k] = BIGF; way_reg[k] = 0; }
        #pragma unroll
        for (int k = 0; k < 5; ++k) ur_reg[k] = __shfl(u_lane, p_reg[k], 64); // u[p[j]]

        int j0 = 0;
        for (;;) {
            int l0 = j0 & 63, k0 = j0 >> 6;            // uniform (SGPR)
            int i0 = rl5(p_reg, k0, l0);
            if (i0 == 0) break;
            float ui0 = rl5f(ur_reg, k0, l0);
            if (lane == l0) usedm |= (1u << k0);
            treemask |= (1u << i0);                     // uniform

            int rowbase = (i0 - 1) * STR + lane;
            float cur[5];
            #pragma unroll
            for (int k = 0; k < 5; ++k) cur[k] = ca[rowbase + (k << 6)];

            float bestv = BIGF; int bestj = 0x7FFFFFFF;
            #pragma unroll
            for (int k = 0; k < 5; ++k) {
                int j = lane + (k << 6);
                bool act = (j <= MCOL);
                bool us  = ((usedm >> k) & 1u) != 0u;
                float cu = cur[k] - ui0 - vloc[k];
                if (act && !us && cu < minv[k]) { minv[k] = cu; way_reg[k] = j0; }
                float mk = (act && !us) ? minv[k] : BIGF;
                if (mk < bestv) { bestv = mk; bestj = j; }  // ascending j per lane
            }
            // wave argmin: DPP value-min, broadcast, then DPP index-min among equals
            float mv = wave_min_f(bestv);
            float delta = __int_as_float(
                __builtin_amdgcn_readlane(__float_as_int(mv), 63));
            int cand = (bestv == delta) ? bestj : 0x7FFFFFFF;
            int cm = wave_min_i(cand);
            int j1 = __builtin_amdgcn_readlane(cm, 63);

            #pragma unroll
            for (int k = 0; k < 5; ++k) {
                bool us = ((usedm >> k) & 1u) != 0u;
                if (us) { vloc[k] -= delta; ur_reg[k] += delta; }
                else if (lane + (k << 6) <= MCOL) minv[k] -= delta;
            }
            if (lane <= NROW && ((treemask >> lane) & 1u)) u_lane += delta;
            j0 = j1;
        }
        // augment: p[j0] = p[way[j0]] walking back to col 0 (uniform readlanes)
        while (j0 != 0) {
            int l0 = j0 & 63, k0 = j0 >> 6;
            int jn = rl5(way_reg, k0, l0);
            int pn = rl5(p_reg, jn >> 6, jn & 63);
            #pragma unroll
            for (int k = 0; k < 5; ++k)
                if (k == k0 && lane == l0) p_reg[k] = pn;
            j0 = jn;
        }
    }

    __builtin_amdgcn_s_setprio(0);

    // ---- extraction: row_ind/col_ind in ascending query order ----
    const size_t ROWB = (size_t)BS * NQ * NTGT;
    const size_t COLB = ROWB + (size_t)BS * TT;
    int base = 0;
    #pragma unroll
    for (int k = 0; k < 5; ++k) {
        int pk1 = (k < 4) ? __shfl(p_reg[k + 1], 0, 64) : 0;   // p[64(k+1)]
        int psh = __shfl(p_reg[k], (lane + 1) & 63, 64);       // p[64k + lane+1]
        int q = (k << 6) | lane;
        int a = (lane == 63) ? pk1 : psh;                      // = p[q+1]
        if (q >= MCOL) a = 0;
        unsigned long long mb = __ballot(a > 0);
        int pos = base + __popcll(mb & ((1ull << lane) - 1ull));
        if (a > 0) {
            out[ROWB + (size_t)b * TT + pos] = (float)q;
            out[COLB + (size_t)b * TT + pos] = (float)(a - 1);
        }
        base += __popcll(mb);
    }
}

extern "C" void kernel_launch(void* const* d_in, const int* in_sizes, int n_in,
                              void* d_out, int out_size, void* d_ws, size_t ws_size,
                              hipStream_t stream) {
    const float* logits = (const float*)d_in[0];   // (64,300,2)
    const float* boxes  = (const float*)d_in[1];   // (64,300,4)
    const float* tgt    = (const float*)d_in[2];   // (1024,4)
    float* out = (float*)d_out;

    // blocks 0..63: hungarian (self-contained); blocks 64..19263: cost matrix (1 q each)
    fused_kernel<<<dim3(BS + BS*NQ), 256, 0, stream>>>(logits, boxes, tgt, out);
}